// Round 9
// baseline (190.616 us; speedup 1.0000x reference)
//
#include <hip/hip_runtime.h>
#include <hip/hip_bf16.h>

// Problem constants (fixed by setup_inputs)
#define BS   4
#define NQ   6400
#define DIMS 256
#define NH   8
#define NP   4
#define GW   80
#define GH   80

typedef __hip_bfloat16 bf16;
typedef unsigned short ushort;
typedef __attribute__((ext_vector_type(8))) short short8;   // 8 bf16 (MFMA A/B frag)
typedef __attribute__((ext_vector_type(4))) float floatx4;  // MFMA C/D frag

union bfu { bf16 h; ushort s; };
__device__ __forceinline__ ushort f2bs(float x) { bfu u; u.h = __float2bfloat16(x); return u.s; }
__device__ __forceinline__ float bs2f(ushort s) { return __uint_as_float(((unsigned)s) << 16); }
__device__ __forceinline__ float ldin(const void* p, size_t i, int isf) {
    return isf ? ((const float*)p)[i] : bs2f(((const ushort*)p)[i]);
}

// async global->LDS DMA, 16B per lane (dest = ldsbase + lane*16)
__device__ __forceinline__ void gl_lds16(const void* gsrc, void* ldst) {
    __builtin_amdgcn_global_load_lds(
        (const __attribute__((address_space(1))) unsigned int*)gsrc,
        (__attribute__((address_space(3))) unsigned int*)ldst,
        16, 0, 0);
}

// ---------------------------------------------------------------------------
// Self-detection: f32-packed data read as bf16 shows impossible exponents.
// Scans the SAME fixed 4096-ushort window of query in every caller ->
// deterministic, identical result in every block (no cross-block comms).
// ---------------------------------------------------------------------------
__device__ __forceinline__ int self_detect(const ushort* __restrict__ q, int tid) {
    int bad = 0;
    const uint4 u0 = ((const uint4*)q)[tid * 2];
    const uint4 u1 = ((const uint4*)q)[tid * 2 + 1];
    const unsigned w[8] = { u0.x, u0.y, u0.z, u0.w, u1.x, u1.y, u1.z, u1.w };
    #pragma unroll
    for (int j = 0; j < 8; ++j) {
        if (((w[j] >> 7)  & 0xFF) > 160) bad = 1;
        if (((w[j] >> 23) & 0xFF) > 160) bad = 1;
    }
    return __any(bad) ? 1 : 0;   // wave-uniform; same data in all blocks
}

// ---------------------------------------------------------------------------
// Merged prep: blocks [0,899) do weight transpose+convert; blocks [899,7299)
// do query/voxbev f32->bf16 conversion. Every block self-detects dtype;
// block 0 publishes the flag for the downstream kernels.
// ---------------------------------------------------------------------------
__global__ __launch_bounds__(256) void prep_k(
    const void* __restrict__ Wv, const void* __restrict__ bv,
    const void* __restrict__ Woff, const void* __restrict__ boff,
    const void* __restrict__ Wattn, const void* __restrict__ battn,
    const void* __restrict__ Wo, const void* __restrict__ bo,
    int* __restrict__ flagp,
    ushort* __restrict__ WvT, ushort* __restrict__ WoaT, ushort* __restrict__ WoT,
    float* __restrict__ biasv, float* __restrict__ biasoa, float* __restrict__ biaso,
    const void* __restrict__ query, const void* __restrict__ voxbev,
    uint4* __restrict__ qb, uint4* __restrict__ vbv)
{
    const int tid = threadIdx.x;
    const int isf = self_detect((const ushort*)query, tid);
    const int bid = blockIdx.x;
    if (bid == 0 && tid == 0) *flagp = isf;
    if (bid < 899) {
        const int i = bid * 256 + tid;
        const int n1 = 256 * 256, n2 = n1 + 192 * 512, n3 = n2 + 256 * 256;
        const int n4 = n3 + 256, n5 = n4 + 192, n6 = n5 + 256;
        if (i < n1) {
            int n = i >> 8, k = i & 255;
            WvT[i] = f2bs(ldin(Wv, (size_t)k * 256 + n, isf));
        } else if (i < n2) {
            int j = i - n1, n = j >> 9, k = j & 511;
            float v = (n < 128) ? ldin(Woff, (size_t)k * 128 + n, isf)
                                : ldin(Wattn, (size_t)k * 64 + (n - 128), isf);
            WoaT[j] = f2bs(v);
        } else if (i < n3) {
            int j = i - n2, n = j >> 8, k = j & 255;
            WoT[j] = f2bs(ldin(Wo, (size_t)k * 256 + n, isf));
        } else if (i < n4) {
            biasv[i - n3] = ldin(bv, i - n3, isf);
        } else if (i < n5) {
            int j = i - n4;
            biasoa[j] = (j < 128) ? ldin(boff, j, isf) : ldin(battn, j - 128, isf);
        } else if (i < n6) {
            biaso[i - n5] = ldin(bo, i - n5, isf);
        }
    } else {
        if (isf == 0) return;
        const int t = (bid - 899) * 256 + tid;
        const int half = 819200;
        const void* src = (t < half) ? query : voxbev;
        uint4* dst = (t < half) ? qb : vbv;
        const int j = (t < half) ? t : t - half;
        const float4* s = (const float4*)src + (size_t)j * 2;
        float4 a = s[0], b = s[1];
        uint4 o;
        o.x = ((unsigned)f2bs(a.y) << 16) | f2bs(a.x);
        o.y = ((unsigned)f2bs(a.w) << 16) | f2bs(a.z);
        o.z = ((unsigned)f2bs(b.y) << 16) | f2bs(b.x);
        o.w = ((unsigned)f2bs(b.w) << 16) | f2bs(b.z);
        dst[j] = o;
    }
}

// ---------------------------------------------------------------------------
// Panel MFMA GEMM body, round-9: async-DMA staged, occupancy-doubled.
//  - tile 128(M) x 64(N), BK=64, SINGLE buffer, FULL-DRAIN barriers only
//    (round-8's counted-vmcnt raced; this keeps round-7's proven sync shape).
//  - Per K-step: A 16KB (16 x 1KB chunks) + B 8KB (8 chunks) via
//    global_load_lds w=16; 6 DMAs/wave/step, zero VGPR cost.
//  - LDS 24.6KB -> 6 blocks/CU (24 waves): other blocks' MFMAs cover each
//    block's stage drain (race-free TLP instead of intra-block pipelining).
//  - XOR swizzle (8-granule 128B rows): store slot = g ^ (row&7) via
//    pre-swizzled GLOBAL source; read applies same XOR -> 2-way banks (free).
//  - Epilogue: two 64-row halves through f32 bounce (stride 67), coalesced.
// OMODE:
//  O_BF16  : bf16 out + bias, row-major [g][N]
//  O_FINAL : + bias + bf16 residual (qsrc row), out f32 (isf) or bf16
//  O_VPERM : bf16 out + bias, head-split layout [s][h][q][32] (GEMM-1)
//  O_OAPERM: bf16 out + bias, per-(b,h) 24-short records (GEMM-2)
// ---------------------------------------------------------------------------
enum { A_VAL = 0, A_QCAT = 1, A_PLAIN = 2 };
enum { O_BF16 = 0, O_FINAL = 1, O_VPERM = 2, O_OAPERM = 3 };

#define ABYT 16384               // A tile bytes (128 rows x 128B)
#define BBYT 8192                // B tile bytes (64 rows x 128B)
#define CST  67                  // f32 bounce row stride (floats)
#define SMEMB (ABYT + BBYT)      // 24576 >= bounce 64*67*4 = 17152

template <int AMODE, int OMODE, int KTOT, int NX, int MG>
__device__ __forceinline__ void pgemm_body(
    const int F, char* smem,
    const ushort* __restrict__ Apl, const ushort* __restrict__ BT,
    const float* __restrict__ biasf, void* __restrict__ C,
    const void* __restrict__ query_raw, const void* __restrict__ voxbev_raw,
    const ushort* __restrict__ qb, const ushort* __restrict__ vbv,
    const int isf)
{
    constexpr int N = NX * 64;
    constexpr int NT = KTOT / 64;            // K-steps of 64 shorts
    float* cbf = (float*)smem;

    // XCD-locality swizzle
    const int xcd = F & 7, l = F >> 3;
    const int n = l % NX;
    const int mg = (l / NX) * 8 + xcd;
    if (mg >= MG) return;
    const int bm = mg * 128, bn = n * 64;

    const int tid = threadIdx.x;
    const int lane = tid & 63, wv = tid >> 6;
    const int wm = wv * 32;                  // wave's 32 output rows
    const int fr = lane & 15;
    const int lrow = lane >> 3;              // staging: row within 8-row chunk
    const int lslot = lane & 7;              // staging: 16B slot within 128B row
    const int sg = lslot ^ lrow;             // pre-swizzled source granule

    const ushort* qsrc = isf ? qb  : (const ushort*)query_raw;
    const ushort* vsrc = isf ? vbv : (const ushort*)voxbev_raw;
    const ushort* aph[2] = { nullptr, nullptr };
    if (AMODE == A_PLAIN) {
        aph[0] = Apl + (size_t)bm * DIMS;
    } else {
        const int b = bm / NQ, q0 = bm - (bm / NQ) * NQ;
        aph[0] = ((b & 1) ? vsrc : qsrc) + (size_t)((b >> 1) * NQ + q0) * DIMS;
        if (AMODE == A_QCAT) aph[1] = qsrc + (size_t)(b * NQ + q0) * DIMS;
    }

    floatx4 acc[2][4] = {};

    #pragma unroll
    for (int t = 0; t < NT; ++t) {
        if (t > 0) __syncthreads();          // prev compute done before overwrite
        // ---- stage A: 4 x 1KB chunks per wave (8 rows x 128B each)
        #pragma unroll
        for (int c4 = 0; c4 < 4; ++c4) {
            const int c = wv * 4 + c4;           // A chunk 0..15
            const int row = c * 8 + lrow;        // row&7 == lrow
            const int k = t * 64 + sg * 8;       // shorts
            const ushort* gp;
            if (AMODE == A_QCAT && KTOT == 512)
                gp = aph[k >> 8] + (size_t)row * DIMS + (k & 255);
            else
                gp = aph[0] + (size_t)row * DIMS + k;
            gl_lds16(gp, smem + c * 1024);
        }
        // ---- stage B: 2 x 1KB chunks per wave
        #pragma unroll
        for (int c2 = 0; c2 < 2; ++c2) {
            const int c = wv * 2 + c2;           // B chunk 0..7
            const int row = c * 8 + lrow;
            gl_lds16(&BT[(size_t)(bn + row) * KTOT + t * 64 + sg * 8],
                     smem + ABYT + c * 1024);
        }
        // full drain (defensive; __syncthreads implies it per m97 asm)
        asm volatile("s_waitcnt vmcnt(0)" ::: "memory");
        __syncthreads();

        // ---- compute (swizzled reads: slot = g ^ (row&7) = g ^ (fr&7))
        const short* acur = (const short*)smem;
        const short* bcur = (const short*)(smem + ABYT);
        #pragma unroll
        for (int k0 = 0; k0 < 64; k0 += 32) {
            const int gl = (k0 >> 3) + (lane >> 4);          // granule 0..7
            const int sl = gl ^ (fr & 7);                    // swizzled slot
            short8 af[2], bf[4];
            #pragma unroll
            for (int mt = 0; mt < 2; ++mt)
                af[mt] = *(const short8*)&acur[(wm + mt * 16 + fr) * 64 + sl * 8];
            #pragma unroll
            for (int nt = 0; nt < 4; ++nt)
                bf[nt] = *(const short8*)&bcur[(nt * 16 + fr) * 64 + sl * 8];
            #pragma unroll
            for (int mt = 0; mt < 2; ++mt)
                #pragma unroll
                for (int nt = 0; nt < 4; ++nt)
                    acc[mt][nt] = __builtin_amdgcn_mfma_f32_16x16x32_bf16(
                        af[mt], bf[nt], acc[mt][nt], 0, 0, 0);
        }
    }

    // ---- epilogue: two 64-row halves through f32 bounce (reuses LDS)
    // C/D layout: col=lane&15, row=(lane>>4)*4+reg (m89-verified)
    const int col = lane & 15, rq = (lane >> 4) * 4;
    const int lbase = wm & 63;               // wave's row base within its half
    #pragma unroll
    for (int half = 0; half < 2; ++half) {
        __syncthreads();
        if ((wv >> 1) == half) {
            #pragma unroll
            for (int mt = 0; mt < 2; ++mt)
                #pragma unroll
                for (int nt = 0; nt < 4; ++nt)
                    #pragma unroll
                    for (int r = 0; r < 4; ++r)
                        cbf[(lbase + mt * 16 + rq + r) * CST + nt * 16 + col] =
                            acc[mt][nt][r];
        }
        __syncthreads();

        if (OMODE == O_FINAL && isf) {
            // f32 out: 16 lanes x 16B cover the 64-col row (256B)
            const int r16 = tid >> 4, cc = tid & 15;
            #pragma unroll
            for (int it = 0; it < 4; ++it) {
                const int lr = it * 16 + r16;
                const size_t g = (size_t)(bm + half * 64 + lr);
                float4 x = *(const float4*)&cbf[lr * CST + cc * 4];
                const ushort* rs = qsrc + g * DIMS + bn + cc * 4;  // bf16 residual
                x.x += biasf[bn + cc * 4 + 0] + bs2f(rs[0]);
                x.y += biasf[bn + cc * 4 + 1] + bs2f(rs[1]);
                x.z += biasf[bn + cc * 4 + 2] + bs2f(rs[2]);
                x.w += biasf[bn + cc * 4 + 3] + bs2f(rs[3]);
                *(float4*)((float*)C + g * N + bn + cc * 4) = x;
            }
        } else {
            // bf16 out: 8 lanes x 16B cover the 64-col row (128B)
            const int r8 = tid >> 3, c8 = tid & 7;
            #pragma unroll
            for (int it = 0; it < 2; ++it) {
                const int lr = it * 32 + r8;
                const size_t g = (size_t)(bm + half * 64 + lr);
                float4 x0 = *(const float4*)&cbf[lr * CST + c8 * 8];
                float4 x1 = *(const float4*)&cbf[lr * CST + c8 * 8 + 4];
                float xs[8] = { x0.x, x0.y, x0.z, x0.w, x1.x, x1.y, x1.z, x1.w };
                #pragma unroll
                for (int e = 0; e < 8; ++e) xs[e] += biasf[bn + c8 * 8 + e];
                if (OMODE == O_FINAL) {
                    const ushort* rs = qsrc + g * DIMS + bn + c8 * 8;
                    #pragma unroll
                    for (int e = 0; e < 8; ++e) xs[e] += bs2f(rs[e]);
                }
                uint4 o;
                o.x = ((unsigned)f2bs(xs[1]) << 16) | f2bs(xs[0]);
                o.y = ((unsigned)f2bs(xs[3]) << 16) | f2bs(xs[2]);
                o.z = ((unsigned)f2bs(xs[5]) << 16) | f2bs(xs[4]);
                o.w = ((unsigned)f2bs(xs[7]) << 16) | f2bs(xs[6]);
                ushort* dstp;
                if (OMODE == O_VPERM) {
                    // v layout: [s=bq][h][q][32] (head-split for sample_k L2 locality)
                    const int cc = bn + c8 * 8;
                    const int s = (int)(g / NQ), qq = (int)(g % NQ);
                    dstp = (ushort*)C + ((size_t)(s * 8 + (cc >> 5)) * NQ + qq) * 32
                                      + (cc & 31);
                } else if (OMODE == O_OAPERM) {
                    // off/attn records: [b][h][q][24] = off[16]|attn[8] per (b,h,q)
                    const int cc = bn + c8 * 8;
                    const int bb = (int)(g / NQ), qq = (int)(g % NQ);
                    int hh, off;
                    if (cc < 128) { hh = cc >> 4; off = cc & 15; }
                    else          { hh = (cc - 128) >> 3; off = 16; }
                    dstp = (ushort*)C + ((size_t)(bb * 8 + hh) * NQ + qq) * 24 + off;
                } else {
                    dstp = (ushort*)C + g * N + bn + c8 * 8;
                }
                *(uint4*)dstp = o;
            }
        }
    }
}

// ---------------------------------------------------------------------------
// GEMM-1 + GEMM-2 fused into one launch (independent work):
//  blocks [0,1600)    : v = interleave(q,v) @ Wv -> [s][h][q][32]
//  blocks [1600,2200) : qcat @ [Woff|Wattn]      -> [b][h][q][24] records
// ---------------------------------------------------------------------------
__global__ __launch_bounds__(256, 6) void gemm12_k(
    const ushort* __restrict__ WvT, const float* __restrict__ biasv,
    ushort* __restrict__ v_ws,
    const ushort* __restrict__ WoaT, const float* __restrict__ biasoa,
    ushort* __restrict__ offraw,
    const void* __restrict__ query_raw, const void* __restrict__ voxbev_raw,
    const ushort* __restrict__ qb, const ushort* __restrict__ vbv,
    const int* __restrict__ flagp)
{
    __shared__ __align__(16) char smem[SMEMB];
    const int isf = *flagp;
    const int bid = blockIdx.x;
    if (bid < 1600) {
        pgemm_body<A_VAL, O_VPERM, 256, 4, 400>(bid, smem,
            nullptr, WvT, biasv, (void*)v_ws, query_raw, voxbev_raw, qb, vbv, isf);
    } else {
        pgemm_body<A_QCAT, O_OAPERM, 512, 3, 200>(bid - 1600, smem,
            nullptr, WoaT, biasoa, (void*)offraw, query_raw, voxbev_raw, qb, vbv, isf);
    }
}

// GEMM-4 standalone (depends on sample_k output)
__global__ __launch_bounds__(256, 6) void gemm4_k(
    const ushort* __restrict__ Apl, const ushort* __restrict__ BT,
    const float* __restrict__ biasf, void* __restrict__ C,
    const void* __restrict__ query_raw, const void* __restrict__ voxbev_raw,
    const ushort* __restrict__ qb, const ushort* __restrict__ vbv,
    const int* __restrict__ flagp)
{
    __shared__ __align__(16) char smem[SMEMB];
    const int isf = *flagp;
    pgemm_body<A_PLAIN, O_FINAL, 256, 4, 200>(blockIdx.x, smem,
        Apl, BT, biasf, C, query_raw, voxbev_raw, qb, vbv, isf);
}

// ---------------------------------------------------------------------------
// Fused softmax + coords + bilinear sampling + queue mean (round-2 proven
// structure: head-pinned blocks for L2 locality, 8-deep gather batches).
//  - v is [s][h][cell][32] (O_VPERM), off/attn are [b][h][q][24] (O_OAPERM).
//  - block = (h = xcd, b phased slowly, 64-query chunk): per-XCD hot set =
//    one head's tables (~1.1MB) << 4MB L2 -> gathers served from L2.
// ---------------------------------------------------------------------------
__global__ __launch_bounds__(256) void sample_k(
    const ushort* __restrict__ v,        // [8 s][8 h][6400 cell][32] bf16
    const ushort* __restrict__ offp,     // [4 b][8 h][6400 q][24] bf16
    const void* __restrict__ refpts,     // [8 bq][6400][2] input dtype
    const int* __restrict__ flagp,
    ushort* __restrict__ sampled)        // [4 b][6400 q][256] bf16
{
    const int isf = *flagp;
    __shared__ int   sidx[64][2][17];
    __shared__ float swt [64][2][17];
    const int tid = threadIdx.x;
    const int j = blockIdx.x;            // 3200 blocks
    const int h = j & 7;                 // head pinned to XCD (round-robin %8)
    const int k = j >> 3;                // 0..399
    const int b = k / 100;               // batch phased slowly within XCD
    const int q0 = (k % 100) * 64;

    if (tid < 128) {
        const int lq = tid >> 1, queue = tid & 1;
        const int q = q0 + lq;
        const ushort* rec = offp + ((size_t)(b * 8 + h) * NQ + q) * 24;
        const ushort* al = rec + 16 + queue * 4;
        float l0 = bs2f(al[0]), l1 = bs2f(al[1]), l2 = bs2f(al[2]), l3 = bs2f(al[3]);
        float mx = fmaxf(fmaxf(l0, l1), fmaxf(l2, l3));
        float e0 = __expf(l0 - mx), e1 = __expf(l1 - mx);
        float e2 = __expf(l2 - mx), e3 = __expf(l3 - mx);
        float inv = 0.5f / (e0 + e1 + e2 + e3);      // fold queue-mean 0.5
        const int bq = b * 2 + queue;
        const float rx = ldin(refpts, ((size_t)bq * NQ + q) * 2 + 0, isf);
        const float ry = ldin(refpts, ((size_t)bq * NQ + q) * 2 + 1, isf);
        const ushort* od = rec + queue * 8;
        float ww[4] = { e0 * inv, e1 * inv, e2 * inv, e3 * inv };
        #pragma unroll
        for (int p = 0; p < NP; ++p) {
            const float x = rx * (float)GW + bs2f(od[p * 2 + 0]) - 0.5f;
            const float y = ry * (float)GH + bs2f(od[p * 2 + 1]) - 0.5f;
            const float x0f = floorf(x), y0f = floorf(y);
            const float dx = x - x0f, dy = y - y0f;
            const int x0 = (int)x0f, y0 = (int)y0f;
            const float wp = ww[p];
            const float cw4[4] = { wp * (1.0f - dx) * (1.0f - dy),
                                   wp * dx * (1.0f - dy),
                                   wp * (1.0f - dx) * dy,
                                   wp * dx * dy };
            #pragma unroll
            for (int c = 0; c < 4; ++c) {
                const int xs = x0 + (c & 1), ys = y0 + (c >> 1);
                const bool ok = (unsigned)xs < (unsigned)GW && (unsigned)ys < (unsigned)GH;
                const int xi = min(max(xs, 0), GW - 1);
                const int yi = min(max(ys, 0), GH - 1);
                sidx[lq][queue][p * 4 + c] = yi * GW + xi;
                swt [lq][queue][p * 4 + c] = ok ? cw4[c] : 0.0f;
            }
        }
    }
    __syncthreads();

    const int lq = tid >> 2, d8 = tid & 3;
    const int q = q0 + lq;
    float a[8] = {};
    #pragma unroll
    for (int queue = 0; queue < 2; ++queue) {
        const ushort* vb = v + (((size_t)(b * 2 + queue) * 8 + h) * NQ) * 32 + d8 * 8;
        #pragma unroll
        for (int hf = 0; hf < 2; ++hf) {
            uint4 g[8];
            #pragma unroll
            for (int u = 0; u < 8; ++u) {
                const int ci = sidx[lq][queue][hf * 8 + u];
                g[u] = *(const uint4*)&vb[(size_t)ci * 32];
            }
            __builtin_amdgcn_sched_barrier(0);
            #pragma unroll
            for (int u = 0; u < 8; ++u) {
                const float cw = swt[lq][queue][hf * 8 + u];
                a[0] += cw * bs2f((ushort)g[u].x); a[1] += cw * bs2f((ushort)(g[u].x >> 16));
                a[2] += cw * bs2f((ushort)g[u].y); a[3] += cw * bs2f((ushort)(g[u].y >> 16));
                a[4] += cw * bs2f((ushort)g[u].z); a[5] += cw * bs2f((ushort)(g[u].z >> 16));
                a[6] += cw * bs2f((ushort)g[u].w); a[7] += cw * bs2f((ushort)(g[u].w >> 16));
            }
        }
    }
    uint4 o;
    o.x = ((unsigned)f2bs(a[1]) << 16) | f2bs(a[0]);
    o.y = ((unsigned)f2bs(a[3]) << 16) | f2bs(a[2]);
    o.z = ((unsigned)f2bs(a[5]) << 16) | f2bs(a[4]);
    o.w = ((unsigned)f2bs(a[7]) << 16) | f2bs(a[6]);
    *(uint4*)&sampled[((size_t)b * NQ + q) * DIMS + h * 32 + d8 * 8] = o;
}

// ---------------------------------------------------------------------------
extern "C" void kernel_launch(void* const* d_in, const int* in_sizes, int n_in,
                              void* d_out, int out_size, void* d_ws, size_t ws_size,
                              hipStream_t stream)
{
    const void* query  = d_in[0];
    const void* voxbev = d_in[1];
    const void* refpts = d_in[2];
    // d_in[3] spatial_shapes=[[80,80]], d_in[4] level_start_index=[0]: hardcoded
    const void* Wv   = d_in[5];  const void* bv    = d_in[6];
    const void* Woff = d_in[7];  const void* boff  = d_in[8];
    const void* Wattn= d_in[9];  const void* battn = d_in[10];
    const void* Wo   = d_in[11]; const void* bo    = d_in[12];

    // workspace (~59.8 MB)
    char* p = (char*)d_ws;
    int* flag = (int*)p;             p += 256;
    ushort* WvT  = (ushort*)p;       p += 256 * 256 * 2;
    ushort* WoaT = (ushort*)p;       p += 192 * 512 * 2;
    ushort* WoT  = (ushort*)p;       p += 256 * 256 * 2;
    float* biasv  = (float*)p;       p += 1024;
    float* biasoa = (float*)p;       p += 1024;
    float* biaso  = (float*)p;       p += 1024;
    ushort* qb   = (ushort*)p;       p += (size_t)BS * NQ * DIMS * 2;       // 13.1 MB
    ushort* vbv  = (ushort*)p;       p += (size_t)BS * NQ * DIMS * 2;       // 13.1 MB
    ushort* v_ws = (ushort*)p;       p += (size_t)2 * BS * NQ * DIMS * 2;   // 26.2 MB
    ushort* offraw = (ushort*)p;     p += (size_t)BS * NQ * 192 * 2;        //  9.8 MB
    ushort* sampled = (ushort*)p;    // 13.1 MB

    // 1. merged dtype-detect + weight prep + input conversion
    prep_k<<<7299, 256, 0, stream>>>(Wv, bv, Woff, boff, Wattn, battn, Wo, bo,
                                     flag, WvT, WoaT, WoT, biasv, biasoa, biaso,
                                     query, voxbev, (uint4*)qb, (uint4*)vbv);

    // 2. GEMM-1 (v projection, head-split out) + GEMM-2 (off/attn records)
    gemm12_k<<<2200, 256, 0, stream>>>(WvT, biasv, v_ws, WoaT, biasoa, offraw,
                                       query, voxbev, qb, vbv, flag);

    // 3. fused softmax + coords + bilinear sampling + queue mean (head-blocked)
    sample_k<<<3200, 256, 0, stream>>>(v_ws, offraw, refpts, flag, sampled);

    // 4. out = sampled @ Wo + bo + residual(bf16 query)
    gemm4_k<<<800, 256, 0, stream>>>(sampled, WoT, biaso, d_out,
                                     query, voxbev, qb, vbv, flag);
}

// Round 10
// 181.886 us; speedup vs baseline: 1.0480x; 1.0480x over previous
//
#include <hip/hip_runtime.h>
#include <hip/hip_bf16.h>

// Problem constants (fixed by setup_inputs)
#define BS   4
#define NQ   6400
#define DIMS 256
#define NH   8
#define NP   4
#define GW   80
#define GH   80

typedef __hip_bfloat16 bf16;
typedef unsigned short ushort;
typedef __attribute__((ext_vector_type(8))) short short8;   // 8 bf16 (MFMA A/B frag)
typedef __attribute__((ext_vector_type(4))) float floatx4;  // MFMA C/D frag

union bfu { bf16 h; ushort s; };
__device__ __forceinline__ ushort f2bs(float x) { bfu u; u.h = __float2bfloat16(x); return u.s; }
__device__ __forceinline__ float bs2f(ushort s) { return __uint_as_float(((unsigned)s) << 16); }
__device__ __forceinline__ float ldin(const void* p, size_t i, int isf) {
    return isf ? ((const float*)p)[i] : bs2f(((const ushort*)p)[i]);
}

// async global->LDS DMA, 16B per lane (dest = ldsbase + lane*16)
__device__ __forceinline__ void gl_lds16(const void* gsrc, void* ldst) {
    __builtin_amdgcn_global_load_lds(
        (const __attribute__((address_space(1))) unsigned int*)gsrc,
        (__attribute__((address_space(3))) unsigned int*)ldst,
        16, 0, 0);
}

// ---------------------------------------------------------------------------
// Self-detection: f32-packed data read as bf16 shows impossible exponents.
// Scans the SAME fixed 4096-ushort window of query in every caller ->
// deterministic, identical result in every block (no cross-block comms).
// ---------------------------------------------------------------------------
__device__ __forceinline__ int self_detect(const ushort* __restrict__ q, int tid) {
    int bad = 0;
    const uint4 u0 = ((const uint4*)q)[tid * 2];
    const uint4 u1 = ((const uint4*)q)[tid * 2 + 1];
    const unsigned w[8] = { u0.x, u0.y, u0.z, u0.w, u1.x, u1.y, u1.z, u1.w };
    #pragma unroll
    for (int j = 0; j < 8; ++j) {
        if (((w[j] >> 7)  & 0xFF) > 160) bad = 1;
        if (((w[j] >> 23) & 0xFF) > 160) bad = 1;
    }
    return __any(bad) ? 1 : 0;   // wave-uniform; same data in all blocks
}

// ---------------------------------------------------------------------------
// Merged prep: blocks [0,899) do weight transpose+convert; blocks [899,7299)
// do query/voxbev f32->bf16 conversion. Every block self-detects dtype;
// block 0 publishes the flag for the downstream kernels.
// ---------------------------------------------------------------------------
__global__ __launch_bounds__(256) void prep_k(
    const void* __restrict__ Wv, const void* __restrict__ bv,
    const void* __restrict__ Woff, const void* __restrict__ boff,
    const void* __restrict__ Wattn, const void* __restrict__ battn,
    const void* __restrict__ Wo, const void* __restrict__ bo,
    int* __restrict__ flagp,
    ushort* __restrict__ WvT, ushort* __restrict__ WoaT, ushort* __restrict__ WoT,
    float* __restrict__ biasv, float* __restrict__ biasoa, float* __restrict__ biaso,
    const void* __restrict__ query, const void* __restrict__ voxbev,
    uint4* __restrict__ qb, uint4* __restrict__ vbv)
{
    const int tid = threadIdx.x;
    const int isf = self_detect((const ushort*)query, tid);
    const int bid = blockIdx.x;
    if (bid == 0 && tid == 0) *flagp = isf;
    if (bid < 899) {
        const int i = bid * 256 + tid;
        const int n1 = 256 * 256, n2 = n1 + 192 * 512, n3 = n2 + 256 * 256;
        const int n4 = n3 + 256, n5 = n4 + 192, n6 = n5 + 256;
        if (i < n1) {
            int n = i >> 8, k = i & 255;
            WvT[i] = f2bs(ldin(Wv, (size_t)k * 256 + n, isf));
        } else if (i < n2) {
            int j = i - n1, n = j >> 9, k = j & 511;
            float v = (n < 128) ? ldin(Woff, (size_t)k * 128 + n, isf)
                                : ldin(Wattn, (size_t)k * 64 + (n - 128), isf);
            WoaT[j] = f2bs(v);
        } else if (i < n3) {
            int j = i - n2, n = j >> 8, k = j & 255;
            WoT[j] = f2bs(ldin(Wo, (size_t)k * 256 + n, isf));
        } else if (i < n4) {
            biasv[i - n3] = ldin(bv, i - n3, isf);
        } else if (i < n5) {
            int j = i - n4;
            biasoa[j] = (j < 128) ? ldin(boff, j, isf) : ldin(battn, j - 128, isf);
        } else if (i < n6) {
            biaso[i - n5] = ldin(bo, i - n5, isf);
        }
    } else {
        if (isf == 0) return;
        const int t = (bid - 899) * 256 + tid;
        const int half = 819200;
        const void* src = (t < half) ? query : voxbev;
        uint4* dst = (t < half) ? qb : vbv;
        const int j = (t < half) ? t : t - half;
        const float4* s = (const float4*)src + (size_t)j * 2;
        float4 a = s[0], b = s[1];
        uint4 o;
        o.x = ((unsigned)f2bs(a.y) << 16) | f2bs(a.x);
        o.y = ((unsigned)f2bs(a.w) << 16) | f2bs(a.z);
        o.z = ((unsigned)f2bs(b.y) << 16) | f2bs(b.x);
        o.w = ((unsigned)f2bs(b.w) << 16) | f2bs(b.z);
        dst[j] = o;
    }
}

// ---------------------------------------------------------------------------
// Panel MFMA GEMM body, round-10: round-7 sync shape (BK=128, single buffer,
// FULL-DRAIN barriers — proven race-free) with WIDE n-tiles for 256-col GEMMs.
//  - NW=1: tile 128x64 (GEMM-2, N=192) — identical to round-7 path.
//  - NW=2: tile 128x128 (GEMM-1/4)  — staged A feeds 2x MFMAs per drain;
//    block count halves -> half the drain events. LDS 64KB -> 2 blocks/CU;
//    2 blocks x ~620cy MFMA/step covers the ~900cy stage drain.
//  - A tile (32KB) + B tile (16KB*NW) staged via global_load_lds width=16
//    (zero VGPR cost, all chunk-DMAs of a step in flight).
//  - XOR swizzle (16-granule 256B rows): store slot = g ^ (row&15) via
//    pre-swizzled GLOBAL source; read applies same XOR -> <=2-way (free).
//  - Epilogue: f32 LDS bounce; NW=1 single 128-row pass (CST 67),
//    NW=2 two 64-row halves (CST 131). Coalesced full-line stores.
// OMODE:
//  O_BF16  : bf16 out + bias, row-major [g][N]
//  O_FINAL : + bias + bf16 residual (qsrc row), out f32 (isf) or bf16
//  O_VPERM : bf16 out + bias, head-split layout [s][h][q][32] (GEMM-1)
//  O_OAPERM: bf16 out + bias, per-(b,h) 24-short records (GEMM-2, NW=1 only)
// ---------------------------------------------------------------------------
enum { A_VAL = 0, A_QCAT = 1, A_PLAIN = 2 };
enum { O_BF16 = 0, O_FINAL = 1, O_VPERM = 2, O_OAPERM = 3 };

#define BKS  128                 // K-step (shorts); row = 256B = 16 granules
#define ABYT (128 * 256)         // A tile bytes (32 KB = 32 x 1KB chunks)
#define SMEMB (ABYT + 2 * 64 * 256)   // 65536 (NW=2 worst case; m132 precedent)

template <int AMODE, int OMODE, int KTOT, int NW, int NXW, int MG>
__device__ __forceinline__ void pgemm_body(
    const int F, char* smem,
    const ushort* __restrict__ Apl, const ushort* __restrict__ BT,
    const float* __restrict__ biasf, void* __restrict__ C,
    const void* __restrict__ query_raw, const void* __restrict__ voxbev_raw,
    const ushort* __restrict__ qb, const ushort* __restrict__ vbv,
    const int isf)
{
    constexpr int N = NW * 64 * NXW;         // full output width
    constexpr int TW = NW * 64;              // this block's tile width
    constexpr int NT = KTOT / BKS;
    constexpr int CSTW = (NW == 1) ? 67 : 131;
    char* abuf = smem;
    char* bbuf = smem + ABYT;
    float* cbf = (float*)smem;

    // XCD-locality swizzle
    const int xcd = F & 7, l = F >> 3;
    const int n = l % NXW;
    const int mg = (l / NXW) * 8 + xcd;
    if (mg >= MG) return;
    const int bm = mg * 128, bn = n * TW;

    const int tid = threadIdx.x;
    const int lane = tid & 63, wv = tid >> 6;
    const int wm = wv * 32;                  // wave's 32 output rows
    const int fr = lane & 15;
    const int srow = lane >> 4;              // staging: row within 4-row chunk
    const int sslot = lane & 15;             // staging: 16B slot within 256B row

    const ushort* qsrc = isf ? qb  : (const ushort*)query_raw;
    const ushort* vsrc = isf ? vbv : (const ushort*)voxbev_raw;
    const ushort* aph[2] = { nullptr, nullptr };
    if (AMODE == A_PLAIN) {
        aph[0] = Apl + (size_t)bm * DIMS;
    } else {
        const int b = bm / NQ, q0 = bm - (bm / NQ) * NQ;
        aph[0] = ((b & 1) ? vsrc : qsrc) + (size_t)((b >> 1) * NQ + q0) * DIMS;
        if (AMODE == A_QCAT) aph[1] = qsrc + (size_t)(b * NQ + q0) * DIMS;
    }

    floatx4 acc[2][4 * NW] = {};

    #pragma unroll
    for (int t = 0; t < NT; ++t) {
        if (t > 0) __syncthreads();          // prev compute done before overwrite
        // ---- stage A: 8 x 1KB chunks per wave (4 rows x 256B each)
        #pragma unroll
        for (int c8 = 0; c8 < 8; ++c8) {
            const int c = wv * 8 + c8;           // A chunk 0..31
            const int row = c * 4 + srow;
            const int g = sslot ^ (row & 15);    // inverse-swizzled src granule
            const int k = t * BKS + g * 8;       // shorts
            const ushort* gp;
            if (AMODE == A_QCAT && KTOT == 512)
                gp = aph[k >> 8] + (size_t)row * DIMS + (k & 255);
            else
                gp = aph[0] + (size_t)row * DIMS + k;
            gl_lds16(gp, abuf + c * 1024);
        }
        // ---- stage B: 4*NW x 1KB chunks per wave
        #pragma unroll
        for (int cb = 0; cb < 4 * NW; ++cb) {
            const int c = wv * 4 * NW + cb;      // B chunk 0..16*NW-1
            const int row = c * 4 + srow;
            const int g = sslot ^ (row & 15);
            gl_lds16(&BT[(size_t)(bn + row) * KTOT + t * BKS + g * 8],
                     bbuf + c * 1024);
        }
        // full drain (defensive; __syncthreads implies it per m97 asm)
        asm volatile("s_waitcnt vmcnt(0)" ::: "memory");
        __syncthreads();

        // ---- compute on staged tile (swizzled reads: slot = g ^ (row&15))
        #pragma unroll
        for (int k0 = 0; k0 < BKS; k0 += 32) {
            const int gl = (k0 >> 3) + (lane >> 4);          // granule 0..15
            const int sl = gl ^ fr;                          // swizzled slot
            short8 af[2], bf[4 * NW];
            #pragma unroll
            for (int mt = 0; mt < 2; ++mt)
                af[mt] = *(const short8*)(abuf + (wm + mt * 16 + fr) * 256
                                               + sl * 16);
            #pragma unroll
            for (int nt = 0; nt < 4 * NW; ++nt)
                bf[nt] = *(const short8*)(bbuf + (nt * 16 + fr) * 256
                                               + sl * 16);
            #pragma unroll
            for (int mt = 0; mt < 2; ++mt)
                #pragma unroll
                for (int nt = 0; nt < 4 * NW; ++nt)
                    acc[mt][nt] = __builtin_amdgcn_mfma_f32_16x16x32_bf16(
                        af[mt], bf[nt], acc[mt][nt], 0, 0, 0);
        }
    }

    // C/D layout: col=lane&15, row=(lane>>4)*4+reg (m89-verified)
    const int col = lane & 15, rq = (lane >> 4) * 4;

    if (NW == 1) {
        // ---- epilogue (round-7 path): single 128-row pass, CST 67
        __syncthreads();
        #pragma unroll
        for (int mt = 0; mt < 2; ++mt)
            #pragma unroll
            for (int nt = 0; nt < 4; ++nt)
                #pragma unroll
                for (int r = 0; r < 4; ++r)
                    cbf[(wm + mt * 16 + rq + r) * 67 + nt * 16 + col] =
                        acc[mt][nt][r];
        __syncthreads();

        if (OMODE == O_FINAL && isf) {
            const int r16 = tid >> 4, cc = tid & 15;
            #pragma unroll
            for (int it = 0; it < 8; ++it) {
                const int lr = it * 16 + r16;
                const size_t g = (size_t)(bm + lr);
                float4 x = *(const float4*)&cbf[lr * 67 + cc * 4];
                const ushort* rs = qsrc + g * DIMS + bn + cc * 4;
                x.x += biasf[bn + cc * 4 + 0] + bs2f(rs[0]);
                x.y += biasf[bn + cc * 4 + 1] + bs2f(rs[1]);
                x.z += biasf[bn + cc * 4 + 2] + bs2f(rs[2]);
                x.w += biasf[bn + cc * 4 + 3] + bs2f(rs[3]);
                *(float4*)((float*)C + g * N + bn + cc * 4) = x;
            }
        } else {
            const int r8 = tid >> 3, c8 = tid & 7;
            #pragma unroll
            for (int it = 0; it < 4; ++it) {
                const int lr = it * 32 + r8;
                const size_t g = (size_t)(bm + lr);
                float4 x0 = *(const float4*)&cbf[lr * 67 + c8 * 8];
                float4 x1 = *(const float4*)&cbf[lr * 67 + c8 * 8 + 4];
                float xs[8] = { x0.x, x0.y, x0.z, x0.w, x1.x, x1.y, x1.z, x1.w };
                #pragma unroll
                for (int e = 0; e < 8; ++e) xs[e] += biasf[bn + c8 * 8 + e];
                if (OMODE == O_FINAL) {
                    const ushort* rs = qsrc + g * DIMS + bn + c8 * 8;
                    #pragma unroll
                    for (int e = 0; e < 8; ++e) xs[e] += bs2f(rs[e]);
                }
                uint4 o;
                o.x = ((unsigned)f2bs(xs[1]) << 16) | f2bs(xs[0]);
                o.y = ((unsigned)f2bs(xs[3]) << 16) | f2bs(xs[2]);
                o.z = ((unsigned)f2bs(xs[5]) << 16) | f2bs(xs[4]);
                o.w = ((unsigned)f2bs(xs[7]) << 16) | f2bs(xs[6]);
                ushort* dstp;
                if (OMODE == O_VPERM) {
                    const int cc = bn + c8 * 8;
                    const int s = (int)(g / NQ), qq = (int)(g % NQ);
                    dstp = (ushort*)C + ((size_t)(s * 8 + (cc >> 5)) * NQ + qq) * 32
                                      + (cc & 31);
                } else if (OMODE == O_OAPERM) {
                    const int cc = bn + c8 * 8;
                    const int bb = (int)(g / NQ), qq = (int)(g % NQ);
                    int hh, off;
                    if (cc < 128) { hh = cc >> 4; off = cc & 15; }
                    else          { hh = (cc - 128) >> 3; off = 16; }
                    dstp = (ushort*)C + ((size_t)(bb * 8 + hh) * NQ + qq) * 24 + off;
                } else {
                    dstp = (ushort*)C + g * N + bn + c8 * 8;
                }
                *(uint4*)dstp = o;
            }
        }
    } else {
        // ---- epilogue (NW=2): two 64-row halves, 128 cols, CST 131
        const int lbase = wm & 63;
        #pragma unroll
        for (int half = 0; half < 2; ++half) {
            __syncthreads();
            if ((wv >> 1) == half) {
                #pragma unroll
                for (int mt = 0; mt < 2; ++mt)
                    #pragma unroll
                    for (int nt = 0; nt < 8; ++nt)
                        #pragma unroll
                        for (int r = 0; r < 4; ++r)
                            cbf[(lbase + mt * 16 + rq + r) * 131 + nt * 16 + col] =
                                acc[mt][nt][r];
            }
            __syncthreads();

            if (OMODE == O_FINAL && isf) {
                // f32 out: 32 lanes x 16B cover the 128-col row (512B)
                const int r32 = tid >> 5, cc = tid & 31;
                #pragma unroll
                for (int it = 0; it < 8; ++it) {
                    const int lr = it * 8 + r32;
                    const size_t g = (size_t)(bm + half * 64 + lr);
                    float4 x = *(const float4*)&cbf[lr * 131 + cc * 4];
                    const ushort* rs = qsrc + g * DIMS + bn + cc * 4;
                    x.x += biasf[bn + cc * 4 + 0] + bs2f(rs[0]);
                    x.y += biasf[bn + cc * 4 + 1] + bs2f(rs[1]);
                    x.z += biasf[bn + cc * 4 + 2] + bs2f(rs[2]);
                    x.w += biasf[bn + cc * 4 + 3] + bs2f(rs[3]);
                    *(float4*)((float*)C + g * N + bn + cc * 4) = x;
                }
            } else {
                // bf16 out: 16 lanes x 16B cover the 128-col row (256B)
                const int r16 = tid >> 4, cc = tid & 15;
                #pragma unroll
                for (int it = 0; it < 4; ++it) {
                    const int lr = it * 16 + r16;
                    const size_t g = (size_t)(bm + half * 64 + lr);
                    float4 x0 = *(const float4*)&cbf[lr * 131 + cc * 8];
                    float4 x1 = *(const float4*)&cbf[lr * 131 + cc * 8 + 4];
                    float xs[8] = { x0.x, x0.y, x0.z, x0.w, x1.x, x1.y, x1.z, x1.w };
                    #pragma unroll
                    for (int e = 0; e < 8; ++e) xs[e] += biasf[bn + cc * 8 + e];
                    if (OMODE == O_FINAL) {
                        const ushort* rs = qsrc + g * DIMS + bn + cc * 8;
                        #pragma unroll
                        for (int e = 0; e < 8; ++e) xs[e] += bs2f(rs[e]);
                    }
                    uint4 o;
                    o.x = ((unsigned)f2bs(xs[1]) << 16) | f2bs(xs[0]);
                    o.y = ((unsigned)f2bs(xs[3]) << 16) | f2bs(xs[2]);
                    o.z = ((unsigned)f2bs(xs[5]) << 16) | f2bs(xs[4]);
                    o.w = ((unsigned)f2bs(xs[7]) << 16) | f2bs(xs[6]);
                    ushort* dstp;
                    if (OMODE == O_VPERM) {
                        const int cc2 = bn + cc * 8;
                        const int s = (int)(g / NQ), qq = (int)(g % NQ);
                        dstp = (ushort*)C
                             + ((size_t)(s * 8 + (cc2 >> 5)) * NQ + qq) * 32
                             + (cc2 & 31);
                    } else {
                        dstp = (ushort*)C + g * N + bn + cc * 8;
                    }
                    *(uint4*)dstp = o;
                }
            }
        }
    }
}

// ---------------------------------------------------------------------------
// GEMM-1 + GEMM-2 fused into one launch (independent work):
//  blocks [0,800)    : v = interleave(q,v) @ Wv -> [s][h][q][32]  (128x128)
//  blocks [800,1400) : qcat @ [Woff|Wattn]      -> [b][h][q][24]  (128x64)
// ---------------------------------------------------------------------------
__global__ __launch_bounds__(256) void gemm12_k(
    const ushort* __restrict__ WvT, const float* __restrict__ biasv,
    ushort* __restrict__ v_ws,
    const ushort* __restrict__ WoaT, const float* __restrict__ biasoa,
    ushort* __restrict__ offraw,
    const void* __restrict__ query_raw, const void* __restrict__ voxbev_raw,
    const ushort* __restrict__ qb, const ushort* __restrict__ vbv,
    const int* __restrict__ flagp)
{
    __shared__ __align__(16) char smem[SMEMB];
    const int isf = *flagp;
    const int bid = blockIdx.x;
    if (bid < 800) {
        pgemm_body<A_VAL, O_VPERM, 256, 2, 2, 400>(bid, smem,
            nullptr, WvT, biasv, (void*)v_ws, query_raw, voxbev_raw, qb, vbv, isf);
    } else {
        pgemm_body<A_QCAT, O_OAPERM, 512, 1, 3, 200>(bid - 800, smem,
            nullptr, WoaT, biasoa, (void*)offraw, query_raw, voxbev_raw, qb, vbv, isf);
    }
}

// GEMM-4 standalone (depends on sample_k output), 128x128 tiles
__global__ __launch_bounds__(256) void gemm4_k(
    const ushort* __restrict__ Apl, const ushort* __restrict__ BT,
    const float* __restrict__ biasf, void* __restrict__ C,
    const void* __restrict__ query_raw, const void* __restrict__ voxbev_raw,
    const ushort* __restrict__ qb, const ushort* __restrict__ vbv,
    const int* __restrict__ flagp)
{
    __shared__ __align__(16) char smem[SMEMB];
    const int isf = *flagp;
    pgemm_body<A_PLAIN, O_FINAL, 256, 2, 2, 200>(blockIdx.x, smem,
        Apl, BT, biasf, C, query_raw, voxbev_raw, qb, vbv, isf);
}

// ---------------------------------------------------------------------------
// Fused softmax + coords + bilinear sampling + queue mean (round-2 proven
// structure: head-pinned blocks for L2 locality, 8-deep gather batches).
//  - v is [s][h][cell][32] (O_VPERM), off/attn are [b][h][q][24] (O_OAPERM).
//  - block = (h = xcd, b phased slowly, 64-query chunk): per-XCD hot set =
//    one head's tables (~1.1MB) << 4MB L2 -> gathers served from L2.
// ---------------------------------------------------------------------------
__global__ __launch_bounds__(256) void sample_k(
    const ushort* __restrict__ v,        // [8 s][8 h][6400 cell][32] bf16
    const ushort* __restrict__ offp,     // [4 b][8 h][6400 q][24] bf16
    const void* __restrict__ refpts,     // [8 bq][6400][2] input dtype
    const int* __restrict__ flagp,
    ushort* __restrict__ sampled)        // [4 b][6400 q][256] bf16
{
    const int isf = *flagp;
    __shared__ int   sidx[64][2][17];
    __shared__ float swt [64][2][17];
    const int tid = threadIdx.x;
    const int j = blockIdx.x;            // 3200 blocks
    const int h = j & 7;                 // head pinned to XCD (round-robin %8)
    const int k = j >> 3;                // 0..399
    const int b = k / 100;               // batch phased slowly within XCD
    const int q0 = (k % 100) * 64;

    if (tid < 128) {
        const int lq = tid >> 1, queue = tid & 1;
        const int q = q0 + lq;
        const ushort* rec = offp + ((size_t)(b * 8 + h) * NQ + q) * 24;
        const ushort* al = rec + 16 + queue * 4;
        float l0 = bs2f(al[0]), l1 = bs2f(al[1]), l2 = bs2f(al[2]), l3 = bs2f(al[3]);
        float mx = fmaxf(fmaxf(l0, l1), fmaxf(l2, l3));
        float e0 = __expf(l0 - mx), e1 = __expf(l1 - mx);
        float e2 = __expf(l2 - mx), e3 = __expf(l3 - mx);
        float inv = 0.5f / (e0 + e1 + e2 + e3);      // fold queue-mean 0.5
        const int bq = b * 2 + queue;
        const float rx = ldin(refpts, ((size_t)bq * NQ + q) * 2 + 0, isf);
        const float ry = ldin(refpts, ((size_t)bq * NQ + q) * 2 + 1, isf);
        const ushort* od = rec + queue * 8;
        float ww[4] = { e0 * inv, e1 * inv, e2 * inv, e3 * inv };
        #pragma unroll
        for (int p = 0; p < NP; ++p) {
            const float x = rx * (float)GW + bs2f(od[p * 2 + 0]) - 0.5f;
            const float y = ry * (float)GH + bs2f(od[p * 2 + 1]) - 0.5f;
            const float x0f = floorf(x), y0f = floorf(y);
            const float dx = x - x0f, dy = y - y0f;
            const int x0 = (int)x0f, y0 = (int)y0f;
            const float wp = ww[p];
            const float cw4[4] = { wp * (1.0f - dx) * (1.0f - dy),
                                   wp * dx * (1.0f - dy),
                                   wp * (1.0f - dx) * dy,
                                   wp * dx * dy };
            #pragma unroll
            for (int c = 0; c < 4; ++c) {
                const int xs = x0 + (c & 1), ys = y0 + (c >> 1);
                const bool ok = (unsigned)xs < (unsigned)GW && (unsigned)ys < (unsigned)GH;
                const int xi = min(max(xs, 0), GW - 1);
                const int yi = min(max(ys, 0), GH - 1);
                sidx[lq][queue][p * 4 + c] = yi * GW + xi;
                swt [lq][queue][p * 4 + c] = ok ? cw4[c] : 0.0f;
            }
        }
    }
    __syncthreads();

    const int lq = tid >> 2, d8 = tid & 3;
    const int q = q0 + lq;
    float a[8] = {};
    #pragma unroll
    for (int queue = 0; queue < 2; ++queue) {
        const ushort* vb = v + (((size_t)(b * 2 + queue) * 8 + h) * NQ) * 32 + d8 * 8;
        #pragma unroll
        for (int hf = 0; hf < 2; ++hf) {
            uint4 g[8];
            #pragma unroll
            for (int u = 0; u < 8; ++u) {
                const int ci = sidx[lq][queue][hf * 8 + u];
                g[u] = *(const uint4*)&vb[(size_t)ci * 32];
            }
            __builtin_amdgcn_sched_barrier(0);
            #pragma unroll
            for (int u = 0; u < 8; ++u) {
                const float cw = swt[lq][queue][hf * 8 + u];
                a[0] += cw * bs2f((ushort)g[u].x); a[1] += cw * bs2f((ushort)(g[u].x >> 16));
                a[2] += cw * bs2f((ushort)g[u].y); a[3] += cw * bs2f((ushort)(g[u].y >> 16));
                a[4] += cw * bs2f((ushort)g[u].z); a[5] += cw * bs2f((ushort)(g[u].z >> 16));
                a[6] += cw * bs2f((ushort)g[u].w); a[7] += cw * bs2f((ushort)(g[u].w >> 16));
            }
        }
    }
    uint4 o;
    o.x = ((unsigned)f2bs(a[1]) << 16) | f2bs(a[0]);
    o.y = ((unsigned)f2bs(a[3]) << 16) | f2bs(a[2]);
    o.z = ((unsigned)f2bs(a[5]) << 16) | f2bs(a[4]);
    o.w = ((unsigned)f2bs(a[7]) << 16) | f2bs(a[6]);
    *(uint4*)&sampled[((size_t)b * NQ + q) * DIMS + h * 32 + d8 * 8] = o;
}

// ---------------------------------------------------------------------------
extern "C" void kernel_launch(void* const* d_in, const int* in_sizes, int n_in,
                              void* d_out, int out_size, void* d_ws, size_t ws_size,
                              hipStream_t stream)
{
    const void* query  = d_in[0];
    const void* voxbev = d_in[1];
    const void* refpts = d_in[2];
    // d_in[3] spatial_shapes=[[80,80]], d_in[4] level_start_index=[0]: hardcoded
    const void* Wv   = d_in[5];  const void* bv    = d_in[6];
    const void* Woff = d_in[7];  const void* boff  = d_in[8];
    const void* Wattn= d_in[9];  const void* battn = d_in[10];
    const void* Wo   = d_in[11]; const void* bo    = d_in[12];

    // workspace (~59.8 MB)
    char* p = (char*)d_ws;
    int* flag = (int*)p;             p += 256;
    ushort* WvT  = (ushort*)p;       p += 256 * 256 * 2;
    ushort* WoaT = (ushort*)p;       p += 192 * 512 * 2;
    ushort* WoT  = (ushort*)p;       p += 256 * 256 * 2;
    float* biasv  = (float*)p;       p += 1024;
    float* biasoa = (float*)p;       p += 1024;
    float* biaso  = (float*)p;       p += 1024;
    ushort* qb   = (ushort*)p;       p += (size_t)BS * NQ * DIMS * 2;       // 13.1 MB
    ushort* vbv  = (ushort*)p;       p += (size_t)BS * NQ * DIMS * 2;       // 13.1 MB
    ushort* v_ws = (ushort*)p;       p += (size_t)2 * BS * NQ * DIMS * 2;   // 26.2 MB
    ushort* offraw = (ushort*)p;     p += (size_t)BS * NQ * 192 * 2;        //  9.8 MB
    ushort* sampled = (ushort*)p;    // 13.1 MB

    // 1. merged dtype-detect + weight prep + input conversion
    prep_k<<<7299, 256, 0, stream>>>(Wv, bv, Woff, boff, Wattn, battn, Wo, bo,
                                     flag, WvT, WoaT, WoT, biasv, biasoa, biaso,
                                     query, voxbev, (uint4*)qb, (uint4*)vbv);

    // 2. GEMM-1 (128x128 tiles, head-split out) + GEMM-2 (128x64, records)
    gemm12_k<<<1400, 256, 0, stream>>>(WvT, biasv, v_ws, WoaT, biasoa, offraw,
                                       query, voxbev, qb, vbv, flag);

    // 3. fused softmax + coords + bilinear sampling + queue mean (head-blocked)
    sample_k<<<3200, 256, 0, stream>>>(v_ws, offraw, refpts, flag, sampled);

    // 4. out = sampled @ Wo + bo + residual(bf16 query)  (128x128 tiles)
    gemm4_k<<<400, 256, 0, stream>>>(sampled, WoT, biaso, d_out,
                                     query, voxbev, qb, vbv, flag);
}

// Round 11
// 178.619 us; speedup vs baseline: 1.0672x; 1.0183x over previous
//
#include <hip/hip_runtime.h>
#include <hip/hip_bf16.h>

// Problem constants (fixed by setup_inputs)
#define BS   4
#define NQ   6400
#define DIMS 256
#define NH   8
#define NP   4
#define GW   80
#define GH   80

typedef __hip_bfloat16 bf16;
typedef unsigned short ushort;
typedef __attribute__((ext_vector_type(8))) short short8;   // 8 bf16 (MFMA A/B frag)
typedef __attribute__((ext_vector_type(4))) float floatx4;  // MFMA C/D frag

union bfu { bf16 h; ushort s; };
__device__ __forceinline__ ushort f2bs(float x) { bfu u; u.h = __float2bfloat16(x); return u.s; }
__device__ __forceinline__ float bs2f(ushort s) { return __uint_as_float(((unsigned)s) << 16); }
__device__ __forceinline__ float ldin(const void* p, size_t i, int isf) {
    return isf ? ((const float*)p)[i] : bs2f(((const ushort*)p)[i]);
}

// async global->LDS DMA, 16B per lane (dest = ldsbase + lane*16)
__device__ __forceinline__ void gl_lds16(const void* gsrc, void* ldst) {
    __builtin_amdgcn_global_load_lds(
        (const __attribute__((address_space(1))) unsigned int*)gsrc,
        (__attribute__((address_space(3))) unsigned int*)ldst,
        16, 0, 0);
}

// barrier with REAL memory-fence semantics for the compiler: plain
// __builtin_amdgcn_s_barrier() is convergent but NOT mayLoad/mayStore, so
// LLVM can hoist ds_reads / sink DMA issues across it (round-8 race root
// cause; rule-#18 hoist failure mode). asm memory clobber pins all mem ops.
__device__ __forceinline__ void barrier_fence() {
    __builtin_amdgcn_sched_barrier(0);
    asm volatile("s_barrier" ::: "memory");
    __builtin_amdgcn_sched_barrier(0);
}

// ---------------------------------------------------------------------------
// Self-detection: f32-packed data read as bf16 shows impossible exponents.
// Scans the SAME fixed 4096-ushort window of query in every caller ->
// deterministic, identical result in every block (no cross-block comms).
// ---------------------------------------------------------------------------
__device__ __forceinline__ int self_detect(const ushort* __restrict__ q, int tid) {
    int bad = 0;
    const uint4 u0 = ((const uint4*)q)[tid * 2];
    const uint4 u1 = ((const uint4*)q)[tid * 2 + 1];
    const unsigned w[8] = { u0.x, u0.y, u0.z, u0.w, u1.x, u1.y, u1.z, u1.w };
    #pragma unroll
    for (int j = 0; j < 8; ++j) {
        if (((w[j] >> 7)  & 0xFF) > 160) bad = 1;
        if (((w[j] >> 23) & 0xFF) > 160) bad = 1;
    }
    return __any(bad) ? 1 : 0;   // wave-uniform; same data in all blocks
}

// ---------------------------------------------------------------------------
// Merged prep: blocks [0,899) do weight transpose+convert; blocks [899,7299)
// do query/voxbev f32->bf16 conversion. Every block self-detects dtype;
// block 0 publishes the flag for the downstream kernels.
// ---------------------------------------------------------------------------
__global__ __launch_bounds__(256) void prep_k(
    const void* __restrict__ Wv, const void* __restrict__ bv,
    const void* __restrict__ Woff, const void* __restrict__ boff,
    const void* __restrict__ Wattn, const void* __restrict__ battn,
    const void* __restrict__ Wo, const void* __restrict__ bo,
    int* __restrict__ flagp,
    ushort* __restrict__ WvT, ushort* __restrict__ WoaT, ushort* __restrict__ WoT,
    float* __restrict__ biasv, float* __restrict__ biasoa, float* __restrict__ biaso,
    const void* __restrict__ query, const void* __restrict__ voxbev,
    uint4* __restrict__ qb, uint4* __restrict__ vbv)
{
    const int tid = threadIdx.x;
    const int isf = self_detect((const ushort*)query, tid);
    const int bid = blockIdx.x;
    if (bid == 0 && tid == 0) *flagp = isf;
    if (bid < 899) {
        const int i = bid * 256 + tid;
        const int n1 = 256 * 256, n2 = n1 + 192 * 512, n3 = n2 + 256 * 256;
        const int n4 = n3 + 256, n5 = n4 + 192, n6 = n5 + 256;
        if (i < n1) {
            int n = i >> 8, k = i & 255;
            WvT[i] = f2bs(ldin(Wv, (size_t)k * 256 + n, isf));
        } else if (i < n2) {
            int j = i - n1, n = j >> 9, k = j & 511;
            float v = (n < 128) ? ldin(Woff, (size_t)k * 128 + n, isf)
                                : ldin(Wattn, (size_t)k * 64 + (n - 128), isf);
            WoaT[j] = f2bs(v);
        } else if (i < n3) {
            int j = i - n2, n = j >> 8, k = j & 255;
            WoT[j] = f2bs(ldin(Wo, (size_t)k * 256 + n, isf));
        } else if (i < n4) {
            biasv[i - n3] = ldin(bv, i - n3, isf);
        } else if (i < n5) {
            int j = i - n4;
            biasoa[j] = (j < 128) ? ldin(boff, j, isf) : ldin(battn, j - 128, isf);
        } else if (i < n6) {
            biaso[i - n5] = ldin(bo, i - n5, isf);
        }
    } else {
        if (isf == 0) return;
        const int t = (bid - 899) * 256 + tid;
        const int half = 819200;
        const void* src = (t < half) ? query : voxbev;
        uint4* dst = (t < half) ? qb : vbv;
        const int j = (t < half) ? t : t - half;
        const float4* s = (const float4*)src + (size_t)j * 2;
        float4 a = s[0], b = s[1];
        uint4 o;
        o.x = ((unsigned)f2bs(a.y) << 16) | f2bs(a.x);
        o.y = ((unsigned)f2bs(a.w) << 16) | f2bs(a.z);
        o.z = ((unsigned)f2bs(b.y) << 16) | f2bs(b.x);
        o.w = ((unsigned)f2bs(b.w) << 16) | f2bs(b.z);
        dst[j] = o;
    }
}

enum { A_VAL = 0, A_QCAT = 1, A_PLAIN = 2 };
enum { O_BF16 = 0, O_FINAL = 1, O_VPERM = 2, O_OAPERM = 3 };

// ---------------------------------------------------------------------------
// PIPELINED GEMM body (gemm12): BK=64, tile 128x64, DOUBLE-buffered
// async-DMA with counted vmcnt (T3/T4), memory-clobber barriers.
//  - Per K-step each wave issues 6 DMAs (4 A-chunks + 2 B-chunks) for tile
//    t+1, then waits vmcnt(6) = "tile t landed" (FIFO retirement, m135),
//    crosses a FENCED barrier, computes tile t. Loads for t+1 stay in
//    flight across compute -> stage drain hidden; 2x24KB = 48KB -> 3
//    blocks/CU of extra TLP.
//  - XOR swizzle (8-granule 128B rows): source granule sg = slot ^ (row&7);
//    read slot sl = gl ^ (fr&7); involution -> identity, <=2-way banks.
//  - Epilogue: single 128-row f32 bounce (CST 67), coalesced stores.
// ---------------------------------------------------------------------------
#define PTILE 24576              // per-buffer bytes: A 16384 + B 8192
#define PSMEM (2 * PTILE)        // 49152 >= bounce 128*67*4 = 34304

template <int AMODE, int OMODE, int KTOT, int NXW, int MG>
__device__ __forceinline__ void pgemm_pipe(
    const int F, char* smem,
    const ushort* __restrict__ Apl, const ushort* __restrict__ BT,
    const float* __restrict__ biasf, void* __restrict__ C,
    const void* __restrict__ query_raw, const void* __restrict__ voxbev_raw,
    const ushort* __restrict__ qb, const ushort* __restrict__ vbv,
    const int isf)
{
    constexpr int N = 64 * NXW;
    constexpr int NT = KTOT / 64;
    float* cbf = (float*)smem;

    // XCD-locality swizzle
    const int xcd = F & 7, l = F >> 3;
    const int n = l % NXW;
    const int mg = (l / NXW) * 8 + xcd;
    if (mg >= MG) return;
    const int bm = mg * 128, bn = n * 64;

    const int tid = threadIdx.x;
    const int lane = tid & 63, wv = tid >> 6;
    const int wm = wv * 32;                  // wave's 32 output rows
    const int fr = lane & 15;
    const int lrow = lane >> 3;              // staging: row within 8-row chunk
    const int lslot = lane & 7;              // staging: 16B slot within 128B row
    const int sg = lslot ^ lrow;             // pre-swizzled source granule

    const ushort* qsrc = isf ? qb  : (const ushort*)query_raw;
    const ushort* vsrc = isf ? vbv : (const ushort*)voxbev_raw;
    const ushort* aph[2] = { nullptr, nullptr };
    if (AMODE == A_PLAIN) {
        aph[0] = Apl + (size_t)bm * DIMS;
    } else {
        const int b = bm / NQ, q0 = bm - (bm / NQ) * NQ;
        aph[0] = ((b & 1) ? vsrc : qsrc) + (size_t)((b >> 1) * NQ + q0) * DIMS;
        if (AMODE == A_QCAT) aph[1] = qsrc + (size_t)(b * NQ + q0) * DIMS;
    }

    // stage tile t into buffer td (6 DMAs per wave)
    auto stage = [&](int td, int t) {
        char* ab = smem + td * PTILE;
        char* bb = ab + 16384;
        #pragma unroll
        for (int c4 = 0; c4 < 4; ++c4) {
            const int c = wv * 4 + c4;           // A chunk 0..15
            const int row = c * 8 + lrow;        // row&7 == lrow
            const int k = t * 64 + sg * 8;       // shorts
            const ushort* gp;
            if (AMODE == A_QCAT && KTOT == 512)
                gp = aph[k >> 8] + (size_t)row * DIMS + (k & 255);
            else
                gp = aph[0] + (size_t)row * DIMS + k;
            gl_lds16(gp, ab + c * 1024);
        }
        #pragma unroll
        for (int c2 = 0; c2 < 2; ++c2) {
            const int c = wv * 2 + c2;           // B chunk 0..7
            const int row = c * 8 + lrow;
            gl_lds16(&BT[(size_t)(bn + row) * KTOT + t * 64 + sg * 8],
                     bb + c * 1024);
        }
    };

    floatx4 acc[2][4] = {};

    stage(0, 0);
    #pragma unroll
    for (int t = 0; t < NT; ++t) {
        if (t + 1 < NT) {
            stage((t + 1) & 1, t + 1);           // prefetch next tile
            __builtin_amdgcn_sched_barrier(0);
            asm volatile("s_waitcnt vmcnt(6)" ::: "memory");  // tile t landed
        } else {
            __builtin_amdgcn_sched_barrier(0);
            asm volatile("s_waitcnt vmcnt(0)" ::: "memory");
        }
        barrier_fence();                         // all waves' tile-t DMAs done

        const short* acur = (const short*)(smem + (t & 1) * PTILE);
        const short* bcur = acur + 8192;         // +16384 bytes
        #pragma unroll
        for (int k0 = 0; k0 < 64; k0 += 32) {
            const int gl = (k0 >> 3) + (lane >> 4);          // granule 0..7
            const int sl = gl ^ (fr & 7);                    // swizzled slot
            short8 af[2], bf[4];
            #pragma unroll
            for (int mt = 0; mt < 2; ++mt)
                af[mt] = *(const short8*)&acur[(wm + mt * 16 + fr) * 64 + sl * 8];
            #pragma unroll
            for (int nt = 0; nt < 4; ++nt)
                bf[nt] = *(const short8*)&bcur[(nt * 16 + fr) * 64 + sl * 8];
            #pragma unroll
            for (int mt = 0; mt < 2; ++mt)
                #pragma unroll
                for (int nt = 0; nt < 4; ++nt)
                    acc[mt][nt] = __builtin_amdgcn_mfma_f32_16x16x32_bf16(
                        af[mt], bf[nt], acc[mt][nt], 0, 0, 0);
        }
        barrier_fence();                         // reads done before overwrite
    }

    // ---- epilogue: single 128-row pass through f32 bounce (reuses LDS)
    __syncthreads();                             // full drain before aliasing
    // C/D layout: col=lane&15, row=(lane>>4)*4+reg (m89-verified)
    const int col = lane & 15, rq = (lane >> 4) * 4;
    #pragma unroll
    for (int mt = 0; mt < 2; ++mt)
        #pragma unroll
        for (int nt = 0; nt < 4; ++nt)
            #pragma unroll
            for (int r = 0; r < 4; ++r)
                cbf[(wm + mt * 16 + rq + r) * 67 + nt * 16 + col] = acc[mt][nt][r];
    __syncthreads();

    if (OMODE == O_FINAL && isf) {
        const int r16 = tid >> 4, cc = tid & 15;
        #pragma unroll
        for (int it = 0; it < 8; ++it) {
            const int lr = it * 16 + r16;
            const size_t g = (size_t)(bm + lr);
            float4 x = *(const float4*)&cbf[lr * 67 + cc * 4];
            const ushort* rs = qsrc + g * DIMS + bn + cc * 4;
            x.x += biasf[bn + cc * 4 + 0] + bs2f(rs[0]);
            x.y += biasf[bn + cc * 4 + 1] + bs2f(rs[1]);
            x.z += biasf[bn + cc * 4 + 2] + bs2f(rs[2]);
            x.w += biasf[bn + cc * 4 + 3] + bs2f(rs[3]);
            *(float4*)((float*)C + g * N + bn + cc * 4) = x;
        }
    } else {
        const int r8 = tid >> 3, c8 = tid & 7;
        #pragma unroll
        for (int it = 0; it < 4; ++it) {
            const int lr = it * 32 + r8;
            const size_t g = (size_t)(bm + lr);
            float4 x0 = *(const float4*)&cbf[lr * 67 + c8 * 8];
            float4 x1 = *(const float4*)&cbf[lr * 67 + c8 * 8 + 4];
            float xs[8] = { x0.x, x0.y, x0.z, x0.w, x1.x, x1.y, x1.z, x1.w };
            #pragma unroll
            for (int e = 0; e < 8; ++e) xs[e] += biasf[bn + c8 * 8 + e];
            if (OMODE == O_FINAL) {
                const ushort* rs = qsrc + g * DIMS + bn + c8 * 8;
                #pragma unroll
                for (int e = 0; e < 8; ++e) xs[e] += bs2f(rs[e]);
            }
            uint4 o;
            o.x = ((unsigned)f2bs(xs[1]) << 16) | f2bs(xs[0]);
            o.y = ((unsigned)f2bs(xs[3]) << 16) | f2bs(xs[2]);
            o.z = ((unsigned)f2bs(xs[5]) << 16) | f2bs(xs[4]);
            o.w = ((unsigned)f2bs(xs[7]) << 16) | f2bs(xs[6]);
            ushort* dstp;
            if (OMODE == O_VPERM) {
                // v layout: [s=bq][h][q][32] (head-split for sample_k L2 locality)
                const int cc = bn + c8 * 8;
                const int s = (int)(g / NQ), qq = (int)(g % NQ);
                dstp = (ushort*)C + ((size_t)(s * 8 + (cc >> 5)) * NQ + qq) * 32
                                  + (cc & 31);
            } else if (OMODE == O_OAPERM) {
                // off/attn records: [b][h][q][24] = off[16]|attn[8] per (b,h,q)
                const int cc = bn + c8 * 8;
                const int bb = (int)(g / NQ), qq = (int)(g % NQ);
                int hh, off;
                if (cc < 128) { hh = cc >> 4; off = cc & 15; }
                else          { hh = (cc - 128) >> 3; off = 16; }
                dstp = (ushort*)C + ((size_t)(bb * 8 + hh) * NQ + qq) * 24 + off;
            } else {
                dstp = (ushort*)C + g * N + bn + c8 * 8;
            }
            *(uint4*)dstp = o;
        }
    }
}

// ---------------------------------------------------------------------------
// WIDE full-drain GEMM body (gemm4, round-10 proven): BK=128, tile 128x128,
// single buffer, full-drain barriers, 64KB LDS.
// ---------------------------------------------------------------------------
#define BKS  128                 // K-step (shorts); row = 256B = 16 granules
#define ABYT (128 * 256)         // A tile bytes (32 KB)
#define WSMEM (ABYT + 2 * 64 * 256)   // 65536

template <int AMODE, int OMODE, int KTOT, int MG>
__device__ __forceinline__ void pgemm_wide(
    const int F, char* smem,
    const ushort* __restrict__ Apl, const ushort* __restrict__ BT,
    const float* __restrict__ biasf, void* __restrict__ C,
    const void* __restrict__ query_raw, const void* __restrict__ voxbev_raw,
    const ushort* __restrict__ qb, const ushort* __restrict__ vbv,
    const int isf)
{
    constexpr int NXW = 2;
    constexpr int N = 256;
    constexpr int NT = KTOT / BKS;
    char* abuf = smem;
    char* bbuf = smem + ABYT;
    float* cbf = (float*)smem;

    const int xcd = F & 7, l = F >> 3;
    const int n = l % NXW;
    const int mg = (l / NXW) * 8 + xcd;
    if (mg >= MG) return;
    const int bm = mg * 128, bn = n * 128;

    const int tid = threadIdx.x;
    const int lane = tid & 63, wv = tid >> 6;
    const int wm = wv * 32;
    const int fr = lane & 15;
    const int srow = lane >> 4;
    const int sslot = lane & 15;

    const ushort* qsrc = isf ? qb  : (const ushort*)query_raw;
    const ushort* vsrc = isf ? vbv : (const ushort*)voxbev_raw;
    const ushort* aph[2] = { nullptr, nullptr };
    if (AMODE == A_PLAIN) {
        aph[0] = Apl + (size_t)bm * DIMS;
    } else {
        const int b = bm / NQ, q0 = bm - (bm / NQ) * NQ;
        aph[0] = ((b & 1) ? vsrc : qsrc) + (size_t)((b >> 1) * NQ + q0) * DIMS;
        if (AMODE == A_QCAT) aph[1] = qsrc + (size_t)(b * NQ + q0) * DIMS;
    }

    floatx4 acc[2][8] = {};

    #pragma unroll
    for (int t = 0; t < NT; ++t) {
        if (t > 0) __syncthreads();
        #pragma unroll
        for (int c8 = 0; c8 < 8; ++c8) {
            const int c = wv * 8 + c8;
            const int row = c * 4 + srow;
            const int g = sslot ^ (row & 15);
            const int k = t * BKS + g * 8;
            const ushort* gp = aph[0] + (size_t)row * DIMS + k;
            gl_lds16(gp, abuf + c * 1024);
        }
        #pragma unroll
        for (int cb = 0; cb < 8; ++cb) {
            const int c = wv * 8 + cb;
            const int row = c * 4 + srow;
            const int g = sslot ^ (row & 15);
            gl_lds16(&BT[(size_t)(bn + row) * KTOT + t * BKS + g * 8],
                     bbuf + c * 1024);
        }
        asm volatile("s_waitcnt vmcnt(0)" ::: "memory");
        __syncthreads();

        #pragma unroll
        for (int k0 = 0; k0 < BKS; k0 += 32) {
            const int gl = (k0 >> 3) + (lane >> 4);
            const int sl = gl ^ fr;
            short8 af[2], bf[8];
            #pragma unroll
            for (int mt = 0; mt < 2; ++mt)
                af[mt] = *(const short8*)(abuf + (wm + mt * 16 + fr) * 256 + sl * 16);
            #pragma unroll
            for (int nt = 0; nt < 8; ++nt)
                bf[nt] = *(const short8*)(bbuf + (nt * 16 + fr) * 256 + sl * 16);
            #pragma unroll
            for (int mt = 0; mt < 2; ++mt)
                #pragma unroll
                for (int nt = 0; nt < 8; ++nt)
                    acc[mt][nt] = __builtin_amdgcn_mfma_f32_16x16x32_bf16(
                        af[mt], bf[nt], acc[mt][nt], 0, 0, 0);
        }
    }

    // epilogue: two 64-row halves, 128 cols, CST 131
    const int col = lane & 15, rq = (lane >> 4) * 4;
    const int lbase = wm & 63;
    #pragma unroll
    for (int half = 0; half < 2; ++half) {
        __syncthreads();
        if ((wv >> 1) == half) {
            #pragma unroll
            for (int mt = 0; mt < 2; ++mt)
                #pragma unroll
                for (int nt = 0; nt < 8; ++nt)
                    #pragma unroll
                    for (int r = 0; r < 4; ++r)
                        cbf[(lbase + mt * 16 + rq + r) * 131 + nt * 16 + col] =
                            acc[mt][nt][r];
        }
        __syncthreads();

        if (OMODE == O_FINAL && isf) {
            const int r32 = tid >> 5, cc = tid & 31;
            #pragma unroll
            for (int it = 0; it < 8; ++it) {
                const int lr = it * 8 + r32;
                const size_t g = (size_t)(bm + half * 64 + lr);
                float4 x = *(const float4*)&cbf[lr * 131 + cc * 4];
                const ushort* rs = qsrc + g * DIMS + bn + cc * 4;
                x.x += biasf[bn + cc * 4 + 0] + bs2f(rs[0]);
                x.y += biasf[bn + cc * 4 + 1] + bs2f(rs[1]);
                x.z += biasf[bn + cc * 4 + 2] + bs2f(rs[2]);
                x.w += biasf[bn + cc * 4 + 3] + bs2f(rs[3]);
                *(float4*)((float*)C + g * N + bn + cc * 4) = x;
            }
        } else {
            const int r16 = tid >> 4, cc = tid & 15;
            #pragma unroll
            for (int it = 0; it < 4; ++it) {
                const int lr = it * 16 + r16;
                const size_t g = (size_t)(bm + half * 64 + lr);
                float4 x0 = *(const float4*)&cbf[lr * 131 + cc * 8];
                float4 x1 = *(const float4*)&cbf[lr * 131 + cc * 8 + 4];
                float xs[8] = { x0.x, x0.y, x0.z, x0.w, x1.x, x1.y, x1.z, x1.w };
                #pragma unroll
                for (int e = 0; e < 8; ++e) xs[e] += biasf[bn + cc * 8 + e];
                if (OMODE == O_FINAL) {
                    const ushort* rs = qsrc + g * DIMS + bn + cc * 8;
                    #pragma unroll
                    for (int e = 0; e < 8; ++e) xs[e] += bs2f(rs[e]);
                }
                uint4 o;
                o.x = ((unsigned)f2bs(xs[1]) << 16) | f2bs(xs[0]);
                o.y = ((unsigned)f2bs(xs[3]) << 16) | f2bs(xs[2]);
                o.z = ((unsigned)f2bs(xs[5]) << 16) | f2bs(xs[4]);
                o.w = ((unsigned)f2bs(xs[7]) << 16) | f2bs(xs[6]);
                ushort* dstp;
                if (OMODE == O_VPERM) {
                    const int cc2 = bn + cc * 8;
                    const int s = (int)(g / NQ), qq = (int)(g % NQ);
                    dstp = (ushort*)C
                         + ((size_t)(s * 8 + (cc2 >> 5)) * NQ + qq) * 32
                         + (cc2 & 31);
                } else {
                    dstp = (ushort*)C + g * N + bn + cc * 8;
                }
                *(uint4*)dstp = o;
            }
        }
    }
}

// ---------------------------------------------------------------------------
// GEMM-1 + GEMM-2 fused into one launch (both pipelined, NW=1):
//  blocks [0,1600)    : v = interleave(q,v) @ Wv -> [s][h][q][32]
//  blocks [1600,2200) : qcat @ [Woff|Wattn]      -> [b][h][q][24] records
// ---------------------------------------------------------------------------
__global__ __launch_bounds__(256) void gemm12_k(
    const ushort* __restrict__ WvT, const float* __restrict__ biasv,
    ushort* __restrict__ v_ws,
    const ushort* __restrict__ WoaT, const float* __restrict__ biasoa,
    ushort* __restrict__ offraw,
    const void* __restrict__ query_raw, const void* __restrict__ voxbev_raw,
    const ushort* __restrict__ qb, const ushort* __restrict__ vbv,
    const int* __restrict__ flagp)
{
    __shared__ __align__(16) char smem[PSMEM];
    const int isf = *flagp;
    const int bid = blockIdx.x;
    if (bid < 1600) {
        pgemm_pipe<A_VAL, O_VPERM, 256, 4, 400>(bid, smem,
            nullptr, WvT, biasv, (void*)v_ws, query_raw, voxbev_raw, qb, vbv, isf);
    } else {
        pgemm_pipe<A_QCAT, O_OAPERM, 512, 3, 200>(bid - 1600, smem,
            nullptr, WoaT, biasoa, (void*)offraw, query_raw, voxbev_raw, qb, vbv, isf);
    }
}

// GEMM-4 standalone (depends on sample_k output), round-10 proven wide body
__global__ __launch_bounds__(256) void gemm4_k(
    const ushort* __restrict__ Apl, const ushort* __restrict__ BT,
    const float* __restrict__ biasf, void* __restrict__ C,
    const void* __restrict__ query_raw, const void* __restrict__ voxbev_raw,
    const ushort* __restrict__ qb, const ushort* __restrict__ vbv,
    const int* __restrict__ flagp)
{
    __shared__ __align__(16) char smem[WSMEM];
    const int isf = *flagp;
    pgemm_wide<A_PLAIN, O_FINAL, 256, 200>(blockIdx.x, smem,
        Apl, BT, biasf, C, query_raw, voxbev_raw, qb, vbv, isf);
}

// ---------------------------------------------------------------------------
// Fused softmax + coords + bilinear sampling + queue mean (round-2 proven
// structure: head-pinned blocks for L2 locality, 8-deep gather batches).
// ---------------------------------------------------------------------------
__global__ __launch_bounds__(256) void sample_k(
    const ushort* __restrict__ v,        // [8 s][8 h][6400 cell][32] bf16
    const ushort* __restrict__ offp,     // [4 b][8 h][6400 q][24] bf16
    const void* __restrict__ refpts,     // [8 bq][6400][2] input dtype
    const int* __restrict__ flagp,
    ushort* __restrict__ sampled)        // [4 b][6400 q][256] bf16
{
    const int isf = *flagp;
    __shared__ int   sidx[64][2][17];
    __shared__ float swt [64][2][17];
    const int tid = threadIdx.x;
    const int j = blockIdx.x;            // 3200 blocks
    const int h = j & 7;                 // head pinned to XCD (round-robin %8)
    const int k = j >> 3;                // 0..399
    const int b = k / 100;               // batch phased slowly within XCD
    const int q0 = (k % 100) * 64;

    if (tid < 128) {
        const int lq = tid >> 1, queue = tid & 1;
        const int q = q0 + lq;
        const ushort* rec = offp + ((size_t)(b * 8 + h) * NQ + q) * 24;
        const ushort* al = rec + 16 + queue * 4;
        float l0 = bs2f(al[0]), l1 = bs2f(al[1]), l2 = bs2f(al[2]), l3 = bs2f(al[3]);
        float mx = fmaxf(fmaxf(l0, l1), fmaxf(l2, l3));
        float e0 = __expf(l0 - mx), e1 = __expf(l1 - mx);
        float e2 = __expf(l2 - mx), e3 = __expf(l3 - mx);
        float inv = 0.5f / (e0 + e1 + e2 + e3);      // fold queue-mean 0.5
        const int bq = b * 2 + queue;
        const float rx = ldin(refpts, ((size_t)bq * NQ + q) * 2 + 0, isf);
        const float ry = ldin(refpts, ((size_t)bq * NQ + q) * 2 + 1, isf);
        const ushort* od = rec + queue * 8;
        float ww[4] = { e0 * inv, e1 * inv, e2 * inv, e3 * inv };
        #pragma unroll
        for (int p = 0; p < NP; ++p) {
            const float x = rx * (float)GW + bs2f(od[p * 2 + 0]) - 0.5f;
            const float y = ry * (float)GH + bs2f(od[p * 2 + 1]) - 0.5f;
            const float x0f = floorf(x), y0f = floorf(y);
            const float dx = x - x0f, dy = y - y0f;
            const int x0 = (int)x0f, y0 = (int)y0f;
            const float wp = ww[p];
            const float cw4[4] = { wp * (1.0f - dx) * (1.0f - dy),
                                   wp * dx * (1.0f - dy),
                                   wp * (1.0f - dx) * dy,
                                   wp * dx * dy };
            #pragma unroll
            for (int c = 0; c < 4; ++c) {
                const int xs = x0 + (c & 1), ys = y0 + (c >> 1);
                const bool ok = (unsigned)xs < (unsigned)GW && (unsigned)ys < (unsigned)GH;
                const int xi = min(max(xs, 0), GW - 1);
                const int yi = min(max(ys, 0), GH - 1);
                sidx[lq][queue][p * 4 + c] = yi * GW + xi;
                swt [lq][queue][p * 4 + c] = ok ? cw4[c] : 0.0f;
            }
        }
    }
    __syncthreads();

    const int lq = tid >> 2, d8 = tid & 3;
    const int q = q0 + lq;
    float a[8] = {};
    #pragma unroll
    for (int queue = 0; queue < 2; ++queue) {
        const ushort* vb = v + (((size_t)(b * 2 + queue) * 8 + h) * NQ) * 32 + d8 * 8;
        #pragma unroll
        for (int hf = 0; hf < 2; ++hf) {
            uint4 g[8];
            #pragma unroll
            for (int u = 0; u < 8; ++u) {
                const int ci = sidx[lq][queue][hf * 8 + u];
                g[u] = *(const uint4*)&vb[(size_t)ci * 32];
            }
            __builtin_amdgcn_sched_barrier(0);
            #pragma unroll
            for (int u = 0; u < 8; ++u) {
                const float cw = swt[lq][queue][hf * 8 + u];
                a[0] += cw * bs2f((ushort)g[u].x); a[1] += cw * bs2f((ushort)(g[u].x >> 16));
                a[2] += cw * bs2f((ushort)g[u].y); a[3] += cw * bs2f((ushort)(g[u].y >> 16));
                a[4] += cw * bs2f((ushort)g[u].z); a[5] += cw * bs2f((ushort)(g[u].z >> 16));
                a[6] += cw * bs2f((ushort)g[u].w); a[7] += cw * bs2f((ushort)(g[u].w >> 16));
            }
        }
    }
    uint4 o;
    o.x = ((unsigned)f2bs(a[1]) << 16) | f2bs(a[0]);
    o.y = ((unsigned)f2bs(a[3]) << 16) | f2bs(a[2]);
    o.z = ((unsigned)f2bs(a[5]) << 16) | f2bs(a[4]);
    o.w = ((unsigned)f2bs(a[7]) << 16) | f2bs(a[6]);
    *(uint4*)&sampled[((size_t)b * NQ + q) * DIMS + h * 32 + d8 * 8] = o;
}

// ---------------------------------------------------------------------------
extern "C" void kernel_launch(void* const* d_in, const int* in_sizes, int n_in,
                              void* d_out, int out_size, void* d_ws, size_t ws_size,
                              hipStream_t stream)
{
    const void* query  = d_in[0];
    const void* voxbev = d_in[1];
    const void* refpts = d_in[2];
    // d_in[3] spatial_shapes=[[80,80]], d_in[4] level_start_index=[0]: hardcoded
    const void* Wv   = d_in[5];  const void* bv    = d_in[6];
    const void* Woff = d_in[7];  const void* boff  = d_in[8];
    const void* Wattn= d_in[9];  const void* battn = d_in[10];
    const void* Wo   = d_in[11]; const void* bo    = d_in[12];

    // workspace (~59.8 MB)
    char* p = (char*)d_ws;
    int* flag = (int*)p;             p += 256;
    ushort* WvT  = (ushort*)p;       p += 256 * 256 * 2;
    ushort* WoaT = (ushort*)p;       p += 192 * 512 * 2;
    ushort* WoT  = (ushort*)p;       p += 256 * 256 * 2;
    float* biasv  = (float*)p;       p += 1024;
    float* biasoa = (float*)p;       p += 1024;
    float* biaso  = (float*)p;       p += 1024;
    ushort* qb   = (ushort*)p;       p += (size_t)BS * NQ * DIMS * 2;       // 13.1 MB
    ushort* vbv  = (ushort*)p;       p += (size_t)BS * NQ * DIMS * 2;       // 13.1 MB
    ushort* v_ws = (ushort*)p;       p += (size_t)2 * BS * NQ * DIMS * 2;   // 26.2 MB
    ushort* offraw = (ushort*)p;     p += (size_t)BS * NQ * 192 * 2;        //  9.8 MB
    ushort* sampled = (ushort*)p;    // 13.1 MB

    // 1. merged dtype-detect + weight prep + input conversion
    prep_k<<<7299, 256, 0, stream>>>(Wv, bv, Woff, boff, Wattn, battn, Wo, bo,
                                     flag, WvT, WoaT, WoT, biasv, biasoa, biaso,
                                     query, voxbev, (uint4*)qb, (uint4*)vbv);

    // 2. GEMM-1 + GEMM-2 (pipelined, counted-vmcnt double-buffer)
    gemm12_k<<<2200, 256, 0, stream>>>(WvT, biasv, v_ws, WoaT, biasoa, offraw,
                                       query, voxbev, qb, vbv, flag);

    // 3. fused softmax + coords + bilinear sampling + queue mean (head-blocked)
    sample_k<<<3200, 256, 0, stream>>>(v_ws, offraw, refpts, flag, sampled);

    // 4. out = sampled @ Wo + bo + residual(bf16 query)  (128x128 tiles)
    gemm4_k<<<400, 256, 0, stream>>>(sampled, WoT, biaso, d_out,
                                     query, voxbev, qb, vbv, flag);
}